// Round 1
// baseline (99.577 us; speedup 1.0000x reference)
//
#include <hip/hip_runtime.h>
#include <stdint.h>

// Problem constants (fixed by setup_inputs)
#define NB 16
#define NTF 4096      // frames T
#define ND 512        // feature dim D
#define NS 8192       // note_size (upsample target, exactly 2*T)
#define ROWS 64       // rows per block
#define BLOCK 256

typedef float v4f __attribute__((ext_vector_type(4)));

static __device__ inline v4f fma4(v4f a, v4f b, v4f c) {
#if __has_builtin(__builtin_elementwise_fma)
    return __builtin_elementwise_fma(a, b, c);
#else
    v4f r;
    r.x = fmaf(a.x, b.x, c.x);
    r.y = fmaf(a.y, b.y, c.y);
    r.z = fmaf(a.z, b.z, c.z);
    r.w = fmaf(a.w, b.w, c.w);
    return r;
#endif
}

// Pack Wg[512][5], Wt[512][10], Wf[512][25] -> Wp[40][512] (col-major per output col)
extern "C" __global__ void pack_w_kernel(const float* __restrict__ Wg,
                                         const float* __restrict__ Wt,
                                         const float* __restrict__ Wf,
                                         float* __restrict__ Wp)
{
    int i = blockIdx.x * BLOCK + threadIdx.x;   // i = c*512 + d
    if (i >= 40 * ND) return;
    int c = i >> 9, d = i & (ND - 1);
    float v;
    if (c < 5)       v = Wg[d * 5  + c];
    else if (c < 15) v = Wt[d * 10 + (c - 5)];
    else             v = Wf[d * 25 + (c - 15)];
    Wp[i] = v;
}

extern "C" __global__ void __launch_bounds__(BLOCK)
hier_main(const float* __restrict__ x,
          const float* __restrict__ bg, const float* __restrict__ bt,
          const float* __restrict__ bf,
          const float* __restrict__ Wp, float* __restrict__ out)
{
    __shared__ float xs[ROWS * 128];     // 32 KB staged x chunk (XOR-swizzled)
    __shared__ float outs[ROWS][41];     // 10.25 KB accums / epilogue (pad 41: 2-way free)

    const int t    = threadIdx.x;
    const int lane = t & 63;
    const int wave = t >> 6;
    const int row  = t & 63;                               // row within block
    const int cg   = __builtin_amdgcn_readfirstlane(wave); // col group 0..3 (wave-uniform)
    const int c0   = cg * 10;
    const int row0 = blockIdx.x * ROWS;                    // global row base

    v4f acc[10];
#pragma unroll
    for (int c = 0; c < 10; ++c) { v4f z = {0.f, 0.f, 0.f, 0.f}; acc[c] = z; }

    const int rx    = row & 7;    // read-side swizzle key
    const int rbase = row * 32;   // float4 slot base for this row

    for (int ch = 0; ch < 4; ++ch) {
        const int d0 = ch * 128;
        // ---- stage 64x128 f32 into LDS; swizzle applied on the GLOBAL source (rule 21) ----
#pragma unroll
        for (int i = 0; i < 8; ++i) {
            const int sbase = wave * 512 + i * 64;   // wave-uniform float4 slot base
            const int slot  = sbase + lane;
            const int srow  = slot >> 5;
            const int sdq   = slot & 31;
            const int gdq   = sdq ^ (srow & 7);
            const float* gp = x + (size_t)(row0 + srow) * ND + d0 + gdq * 4;
            __builtin_amdgcn_global_load_lds(
                (const __attribute__((address_space(1))) unsigned int*)gp,
                (__attribute__((address_space(3))) unsigned int*)((char*)xs + (size_t)sbase * 16),
                16, 0, 0);
        }
        __syncthreads();
        // ---- FMA over chunk: 1 ds_read_b128 + 10 vector FMAs per dq ----
#pragma unroll 4
        for (int dq = 0; dq < 32; ++dq) {
            const v4f x4 = *(const v4f*)&xs[(rbase + (dq ^ rx)) * 4];
            const float* wb = Wp + (size_t)c0 * ND + d0 + dq * 4;  // wave-uniform -> s_load
#pragma unroll
            for (int c = 0; c < 10; ++c) {
                const v4f w4 = *(const v4f*)(wb + (size_t)c * ND);
                acc[c] = fma4(x4, w4, acc[c]);
            }
        }
        __syncthreads();
    }

    // ---- dump per-(row,col) dot products to LDS ----
#pragma unroll
    for (int c = 0; c < 10; ++c) {
        v4f a = acc[c];
        outs[row][c0 + c] = (a.x + a.y) + (a.z + a.w);
    }
    __syncthreads();

    const int b   = row0 / NTF;
    const int tt0 = row0 % NTF;

    // ---- phase A: per-row bias + hierarchical argmax masking (wave 0, one lane per row) ----
    if (t < 64) {
        constexpr int TOWN[10] = {0,1,2,2,2,3,3,3,4,4};
        constexpr int FOWN[25] = {0,1,2,2,2,3,3,3,3,3,3,3,3,4,9,6,8,5,7,1,3,3,3,9,3};
        const int r = t;
        float gl[5]; int gp = 0; float gbest = -INFINITY;
#pragma unroll
        for (int c = 0; c < 5; ++c) {
            float v = outs[r][c] + bg[c];
            gl[c] = v;
            if (v > gbest) { gbest = v; gp = c; }   // first-max (strict >) == jnp.argmax
        }
        float tl[10]; int tp = 0; float tbest = -INFINITY;
#pragma unroll
        for (int k = 0; k < 10; ++k) {
            float v = outs[r][5 + k] + bt[k];
            float m = (TOWN[k] == gp) ? 1.f : 0.f;
            v *= m;                                  // identical arithmetic to reference
            tl[k] = v;
            if (v > tbest) { tbest = v; tp = k; }
        }
#pragma unroll
        for (int c = 0; c < 5; ++c)  outs[r][c] = gl[c];
#pragma unroll
        for (int k = 0; k < 10; ++k) outs[r][5 + k] = tl[k];
#pragma unroll
        for (int f = 0; f < 25; ++f) {
            float v = outs[r][15 + f] + bf[f];
            float m = (FOWN[f] == tp) ? 1.f : 0.f;
            outs[r][15 + f] = v * m;
        }
    }
    __syncthreads();

    // ---- phase B: coalesced streaming writes; block's output regions are contiguous ----
    // group_up [B][S][5]
    {
        float* og = out + ((size_t)b * NS + 2 * (size_t)tt0) * 5;
        for (int i = t; i < 128 * 5; i += BLOCK) og[i] = outs[(i / 5) >> 1][i % 5];
    }
    // tech_up [B][S][10]
    {
        float* ot = out + (size_t)NB * NS * 5 + ((size_t)b * NS + 2 * (size_t)tt0) * 10;
        for (int i = t; i < 128 * 10; i += BLOCK) ot[i] = outs[(i / 10) >> 1][5 + i % 10];
    }
    // final_up [B][S][25]
    {
        float* of = out + (size_t)NB * NS * 15 + ((size_t)b * NS + 2 * (size_t)tt0) * 25;
        for (int i = t; i < 128 * 25; i += BLOCK) of[i] = outs[(i / 25) >> 1][15 + i % 25];
    }
    // frame_level_final_tech_logits [B][T][25]
    {
        float* ofr = out + (size_t)NB * NS * 40 + (size_t)row0 * 25;
        for (int i = t; i < 64 * 25; i += BLOCK) ofr[i] = outs[i / 25][15 + i % 25];
    }
}

extern "C" void kernel_launch(void* const* d_in, const int* in_sizes, int n_in,
                              void* d_out, int out_size, void* d_ws, size_t ws_size,
                              hipStream_t stream)
{
    const float* x  = (const float*)d_in[0];
    const float* Wg = (const float*)d_in[1];
    const float* bg = (const float*)d_in[2];
    const float* Wt = (const float*)d_in[3];
    const float* bt = (const float*)d_in[4];
    const float* Wf = (const float*)d_in[5];
    const float* bf = (const float*)d_in[6];
    float* Wp  = (float*)d_ws;          // 40*512*4 = 80 KB packed weights
    float* outp = (float*)d_out;

    hipLaunchKernelGGL(pack_w_kernel, dim3((40 * ND + BLOCK - 1) / BLOCK), dim3(BLOCK), 0, stream,
                       Wg, Wt, Wf, Wp);
    hipLaunchKernelGGL(hier_main, dim3((NB * NTF) / ROWS), dim3(BLOCK), 0, stream,
                       x, bg, bt, bf, Wp, outp);
}

// Round 2
// 99.020 us; speedup vs baseline: 1.0056x; 1.0056x over previous
//
#include <hip/hip_runtime.h>
#include <stdint.h>

// Problem constants (fixed by setup_inputs)
#define NB 16
#define NTF 4096      // frames T
#define ND 512        // feature dim D
#define NS 8192       // note_size (upsample target, exactly 2*T)
#define NCOL 40       // 5 + 10 + 25 output columns
#define CHUNK 32      // d-chunk in floats (8 float4 slots per row)
#define NCHUNK 16     // 512 / 32

typedef float v4f __attribute__((ext_vector_type(4)));
typedef float v2f __attribute__((ext_vector_type(2)));

static __device__ inline v4f fma4(v4f a, v4f b, v4f c) {
#if __has_builtin(__builtin_elementwise_fma)
    return __builtin_elementwise_fma(a, b, c);
#else
    v4f r;
    r.x = fmaf(a.x, b.x, c.x);
    r.y = fmaf(a.y, b.y, c.y);
    r.z = fmaf(a.z, b.z, c.z);
    r.w = fmaf(a.w, b.w, c.w);
    return r;
#endif
}

// Pack Wg[512][5], Wt[512][10], Wf[512][25] -> Wp[40][512] (row per output col)
extern "C" __global__ void pack_w_kernel(const float* __restrict__ Wg,
                                         const float* __restrict__ Wt,
                                         const float* __restrict__ Wf,
                                         float* __restrict__ Wp)
{
    int i = blockIdx.x * 256 + threadIdx.x;   // i = c*512 + d
    if (i >= NCOL * ND) return;
    int c = i >> 9, d = i & (ND - 1);
    float v;
    if (c < 5)       v = Wg[d * 5  + c];
    else if (c < 15) v = Wt[d * 10 + (c - 5)];
    else             v = Wf[d * 25 + (c - 15)];
    Wp[i] = v;
}

// One wave per block; lane = row; each lane accumulates all 40 columns.
// x chunk + W chunk double-buffered in LDS, staged by global_load_lds(16B),
// counted vmcnt waits, no barriers (single-wave block).
extern "C" __global__ void __launch_bounds__(64, 1)
hier_main(const float* __restrict__ x,
          const float* __restrict__ bg, const float* __restrict__ bt,
          const float* __restrict__ bf,
          const float* __restrict__ Wp, float* __restrict__ out)
{
    // 64 rows x 32 floats = 512 float4 slots = 8 KB per buffer
    __shared__ __align__(128) float xs[2][64 * CHUNK];
    // 40 cols x 32 floats = 320 float4 slots = 5 KB per buffer
    __shared__ __align__(128) float ws[2][NCOL * CHUNK];

    const int lane = threadIdx.x;          // 0..63, = row within block
    const int row0 = blockIdx.x * 64;
    const int rx   = lane & 7;             // read-side swizzle key

    v4f acc[NCOL];
#pragma unroll
    for (int c = 0; c < NCOL; ++c) { v4f z = {0.f, 0.f, 0.f, 0.f}; acc[c] = z; }

    // ---- staging: 8 x-instrs + 5 W-instrs = 13 global_load_lds per chunk ----
    auto stage = [&](int p, int d0) {
#pragma unroll
        for (int i = 0; i < 8; ++i) {
            const int slot = i * 64 + lane;           // 0..511
            const int srow = slot >> 3;
            const int sq   = slot & 7;
            const int gq   = sq ^ (srow & 7);         // source-side swizzle (rule 21)
            const float* gp = x + (size_t)(row0 + srow) * ND + d0 + gq * 4;
            __builtin_amdgcn_global_load_lds(
                (const __attribute__((address_space(1))) unsigned int*)gp,
                (__attribute__((address_space(3))) unsigned int*)((char*)&xs[p][0] + (size_t)(i * 64) * 16),
                16, 0, 0);
        }
#pragma unroll
        for (int j = 0; j < 5; ++j) {
            const int slot = j * 64 + lane;           // 0..319
            const int c    = slot >> 3;
            const int q    = slot & 7;
            const float* gp = Wp + (size_t)c * ND + d0 + q * 4;
            __builtin_amdgcn_global_load_lds(
                (const __attribute__((address_space(1))) unsigned int*)gp,
                (__attribute__((address_space(3))) unsigned int*)((char*)&ws[p][0] + (size_t)(j * 64) * 16),
                16, 0, 0);
        }
    };

    stage(0, 0);
    for (int ch = 0; ch < NCHUNK; ++ch) {
        const int p = ch & 1;
        // drain prior ds_reads before overwriting any buffer (cheap: already consumed)
        asm volatile("s_waitcnt lgkmcnt(0)" ::: "memory");
        if (ch < NCHUNK - 1) {
            stage(p ^ 1, (ch + 1) * CHUNK);
            asm volatile("s_waitcnt vmcnt(13)" ::: "memory");  // current chunk landed
        } else {
            asm volatile("s_waitcnt vmcnt(0)" ::: "memory");
        }
        __builtin_amdgcn_sched_barrier(0);

        const float* xb = &xs[p][(size_t)lane * CHUNK];
        const float* wb = &ws[p][0];
#pragma unroll
        for (int q = 0; q < 8; ++q) {
            const v4f x4 = *(const v4f*)(xb + (size_t)(q ^ rx) * 4);   // swizzled, conflict-free
#pragma unroll
            for (int c = 0; c < NCOL; ++c) {
                const v4f w4 = *(const v4f*)(wb + (size_t)(c * 8 + q) * 4);  // uniform broadcast
                acc[c] = fma4(x4, w4, acc[c]);
            }
        }
    }

    // ---- epilogue: fully in-register per lane (lane = row) ----
    float l[NCOL];
#pragma unroll
    for (int c = 0; c < NCOL; ++c) {
        v4f a = acc[c];
        l[c] = (a.x + a.y) + (a.z + a.w);
    }

    constexpr int TOWN[10] = {0,1,2,2,2,3,3,3,4,4};
    constexpr int FOWN[25] = {0,1,2,2,2,3,3,3,3,3,3,3,3,4,9,6,8,5,7,1,3,3,3,9,3};

    float gl[5]; int gp = 0; float gbest = -INFINITY;
#pragma unroll
    for (int c = 0; c < 5; ++c) {
        float v = l[c] + bg[c];
        gl[c] = v;
        if (v > gbest) { gbest = v; gp = c; }   // strict > == jnp.argmax first-max
    }
    float tl[10]; int tp = 0; float tbest = -INFINITY;
#pragma unroll
    for (int k = 0; k < 10; ++k) {
        float v = (l[5 + k] + bt[k]) * ((TOWN[k] == gp) ? 1.f : 0.f);
        tl[k] = v;
        if (v > tbest) { tbest = v; tp = k; }
    }
    float fl[25];
#pragma unroll
    for (int f = 0; f < 25; ++f) {
        fl[f] = (l[15 + f] + bf[f]) * ((FOWN[f] == tp) ? 1.f : 0.f);
    }

    const int r  = row0 + lane;
    const int b  = r >> 12;        // / 4096
    const int tt = r & (NTF - 1);  // % 4096

    // group_up [B][S][5]: 2 frames x 5, 8B-aligned -> 5x float2
    {
        v2f* og = (v2f*)(out + ((size_t)b * NS + 2 * (size_t)tt) * 5);
#pragma unroll
        for (int j = 0; j < 5; ++j) {
            v2f v; v.x = gl[(2 * j) % 5]; v.y = gl[(2 * j + 1) % 5];
            og[j] = v;
        }
    }
    // tech_up [B][S][10]: 2 frames x 10, 16B-aligned -> 5x float4
    {
        v4f* ot = (v4f*)(out + (size_t)NB * NS * 5 + ((size_t)b * NS + 2 * (size_t)tt) * 10);
#pragma unroll
        for (int j = 0; j < 5; ++j) {
            v4f v;
            v.x = tl[(4 * j)     % 10];
            v.y = tl[(4 * j + 1) % 10];
            v.z = tl[(4 * j + 2) % 10];
            v.w = tl[(4 * j + 3) % 10];
            ot[j] = v;
        }
    }
    // final_up [B][S][25]: 2 frames x 25, 8B-aligned -> 25x float2
    {
        v2f* of = (v2f*)(out + (size_t)NB * NS * 15 + ((size_t)b * NS + 2 * (size_t)tt) * 25);
#pragma unroll
        for (int j = 0; j < 25; ++j) {
            v2f v; v.x = fl[(2 * j) % 25]; v.y = fl[(2 * j + 1) % 25];
            of[j] = v;
        }
    }
    // frame_level_final_tech_logits [B][T][25]: 4B-aligned -> scalar
    {
        float* ofr = out + (size_t)NB * NS * 40 + ((size_t)b * NTF + tt) * 25;
#pragma unroll
        for (int i = 0; i < 25; ++i) ofr[i] = fl[i];
    }
}

extern "C" void kernel_launch(void* const* d_in, const int* in_sizes, int n_in,
                              void* d_out, int out_size, void* d_ws, size_t ws_size,
                              hipStream_t stream)
{
    const float* x  = (const float*)d_in[0];
    const float* Wg = (const float*)d_in[1];
    const float* bg = (const float*)d_in[2];
    const float* Wt = (const float*)d_in[3];
    const float* bt = (const float*)d_in[4];
    const float* Wf = (const float*)d_in[5];
    const float* bf = (const float*)d_in[6];
    float* Wp  = (float*)d_ws;          // 40*512*4 = 80 KB packed weights
    float* outp = (float*)d_out;

    hipLaunchKernelGGL(pack_w_kernel, dim3((NCOL * ND + 255) / 256), dim3(256), 0, stream,
                       Wg, Wt, Wf, Wp);
    hipLaunchKernelGGL(hier_main, dim3((NB * NTF) / 64), dim3(64), 0, stream,
                       x, bg, bt, bf, Wp, outp);
}